// Round 12
// baseline (252.415 us; speedup 1.0000x reference)
//
#include <hip/hip_runtime.h>
#include <hip/hip_bf16.h>
#include <math.h>

typedef __attribute__((ext_vector_type(8))) short short8;
typedef __attribute__((ext_vector_type(4))) float floatx4;
typedef __attribute__((ext_vector_type(16))) float floatx16;
typedef __attribute__((ext_vector_type(4))) unsigned short ushort4v;
typedef __attribute__((ext_vector_type(2))) unsigned uint2v;
typedef unsigned long long u64;

__device__ __forceinline__ unsigned short f32_to_bf16(float f) {
    union { float f; unsigned int u; } v; v.f = f;
    return (unsigned short)((v.u + 0x7fffu + ((v.u >> 16) & 1u)) >> 16);
}
__device__ __forceinline__ float bf16_to_f32(unsigned short s) {
    union { float f; unsigned int u; } v; v.u = ((unsigned)s) << 16; return v.f;
}
__device__ __forceinline__ unsigned pack_bf16x2(float a, float b) {
    __hip_bfloat162 h = __float22bfloat162_rn(make_float2(a, b));
    union { __hip_bfloat162 h; unsigned u; } c; c.h = h; return c.u;
}
// lane l <-> lane l^32 exchange via the COMPILER-EMITTED instruction
// (__builtin_amdgcn_permlane32_swap, gfx950). Builtin only (asm quarantined).
__device__ __forceinline__ void plswap(unsigned &a, unsigned &b) {
    uint2v r = __builtin_amdgcn_permlane32_swap(a, b, false, false);
    a = r[0]; b = r[1];
}

#define GL2LDS16(g, l)                                                        \
    __builtin_amdgcn_global_load_lds(                                         \
        (const __attribute__((address_space(1))) unsigned int*)(g),           \
        (__attribute__((address_space(3))) unsigned int*)(l), 16, 0, 0)

// XOR-swizzle: within each 64-elem chunk, physical 8-group = logical ^ (row&7)
__device__ __forceinline__ int swz(int k, int row) {
    return (k & ~63) | (k & 7) | ((((k >> 3) ^ row) & 7) << 3);
}

// log2(e)/32: folds exp->exp2 and the 1/sqrt(1024) scale into Q
#define QSCALE 0.04508422002f

// ---------------------------------------------------------------------------
// prep: six f32->bf16 swizzled conversions AND mask->bitmask, one launch.
// (r0 proven version, untouched.)
// ---------------------------------------------------------------------------
__global__ __launch_bounds__(256)
void prep(const float* __restrict__ Q, const float* __restrict__ K,
          const float* __restrict__ Wq, const float* __restrict__ Wk,
          const float* __restrict__ Wv, const float* __restrict__ Wo,
          const int* __restrict__ mask,
          unsigned short* __restrict__ Qc, unsigned short* __restrict__ Kc,
          unsigned short* __restrict__ Wqc, unsigned short* __restrict__ Wkc,
          unsigned short* __restrict__ Wvc, unsigned short* __restrict__ Woc,
          u64* __restrict__ Mb) {
    const int r = blockIdx.x;
    if (r < 12288) {
        const float* src; unsigned short* dst; int row;
        if (r < 4096)      { src = Q; dst = Qc; row = r; }
        else if (r < 8192) { src = K; dst = Kc; row = r - 4096; }
        else {
            const int t = r - 8192; const int wi = t >> 10; row = t & 1023;
            src = (wi == 0) ? Wq : (wi == 1) ? Wk : (wi == 2) ? Wv : Wo;
            dst = (wi == 0) ? Wqc : (wi == 1) ? Wkc : (wi == 2) ? Wvc : Woc;
        }
        const int k = threadIdx.x * 4;
        floatx4 v = *(const floatx4*)(src + (size_t)row * 1024 + k);
        ushort4v o;
        #pragma unroll
        for (int j = 0; j < 4; j++) o[j] = f32_to_bf16(v[j]);
        *(ushort4v*)(dst + (size_t)row * 1024 + swz(k, row)) = o;
    } else {
        const int gid = (r - 12288) * 256 + threadIdx.x;
        const int v = mask[gid];
        u64 bal = __ballot(v != 0);
        if ((threadIdx.x & 63) == 0) Mb[gid >> 6] = bal;
    }
}

// ---------------------------------------------------------------------------
// Three projection GEMMs, one launch (grid.z): m97 structure — 128x128 tile,
// BK=64, 16x16x32 MFMA, 4x4 acc tiles per wave (32 MFMA : 16 b128 / BK-step).
// z=0: Qp = (Qc Wq^T + bq) * QSCALE; z=1: Kp; z=2: Vtp (transposed out).
// (r0 proven version, untouched.)
// ---------------------------------------------------------------------------
__global__ __launch_bounds__(256)
void proj3(const unsigned short* __restrict__ Qc, const unsigned short* __restrict__ Kc,
           const unsigned short* __restrict__ Wq, const unsigned short* __restrict__ Wk,
           const unsigned short* __restrict__ Wv,
           const float* __restrict__ bq, const float* __restrict__ bk,
           const float* __restrict__ bv,
           unsigned short* __restrict__ Qp, unsigned short* __restrict__ Kp,
           unsigned short* __restrict__ Vtp) {
    constexpr int K = 1024;
    const int z = blockIdx.z;
    const unsigned short* A = (z == 0) ? Qc : Kc;
    const unsigned short* W = (z == 0) ? Wq : (z == 1) ? Wk : Wv;
    const float* bias = (z == 0) ? bq : (z == 1) ? bk : bv;

    __shared__ unsigned short As[128 * 64];
    __shared__ unsigned short Ws[128 * 64];

    const int tid = threadIdx.x;
    const int w = tid >> 6, lane = tid & 63;
    const int col = lane & 15, quad = lane >> 4;
    const int m0 = blockIdx.x * 128, n0 = blockIdx.y * 128;
    const int wm = (w >> 1) * 64, wn = (w & 1) * 64;

    floatx4 acc[4][4];
    #pragma unroll
    for (int t = 0; t < 4; t++)
        #pragma unroll
        for (int u = 0; u < 4; u++) acc[t][u] = (floatx4){0.f, 0.f, 0.f, 0.f};

    const int lrow = lane >> 3, lcol = (lane & 7) * 8;
    const unsigned short* Ag = A + (size_t)(m0 + w * 32 + lrow) * K + lcol;
    const unsigned short* Wg = W + (size_t)(n0 + w * 32 + lrow) * K + lcol;
    const int po0 = (quad ^ (col & 7)) * 8;
    const int po1 = ((quad + 4) ^ (col & 7)) * 8;

    for (int kb = 0; kb < K; kb += 64) {
        __syncthreads();
        #pragma unroll
        for (int i = 0; i < 4; i++) {
            GL2LDS16(Ag + (size_t)(i * 8) * K + kb, &As[(w * 32 + i * 8) * 64]);
            GL2LDS16(Wg + (size_t)(i * 8) * K + kb, &Ws[(w * 32 + i * 8) * 64]);
        }
        __syncthreads();

        #pragma unroll
        for (int s = 0; s < 2; s++) {
            const int po = s ? po1 : po0;
            short8 af[4], wf[4];
            #pragma unroll
            for (int t = 0; t < 4; t++)
                af[t] = *(const short8*)&As[(wm + t * 16 + col) * 64 + po];
            #pragma unroll
            for (int u = 0; u < 4; u++)
                wf[u] = *(const short8*)&Ws[(wn + u * 16 + col) * 64 + po];
            #pragma unroll
            for (int t = 0; t < 4; t++)
                #pragma unroll
                for (int u = 0; u < 4; u++)
                    acc[t][u] = __builtin_amdgcn_mfma_f32_16x16x32_bf16(af[t], wf[u], acc[t][u], 0, 0, 0);
        }
    }

    #pragma unroll
    for (int u = 0; u < 4; u++) {
        const int n = n0 + wn + u * 16 + col;
        const float bb = bias[n];
        const int ng = (n >> 3) & 7;
        #pragma unroll
        for (int t = 0; t < 4; t++) {
            const int mbase = m0 + wm + t * 16 + quad * 4;
            if (z == 2) {
                // Vtp[b][1024 d][2048 tokens], token dim swizzled by (d&7)
                const int bidx = mbase >> 11;
                const int tl = mbase & 2047;
                const int mg = (mbase >> 3) & 7;
                ushort4v o;
                #pragma unroll
                for (int r = 0; r < 4; r++)
                    o[r] = f32_to_bf16(acc[t][u][r] + bb);
                *(ushort4v*)(Vtp + ((size_t)(bidx * 1024 + n)) * 2048 +
                             (tl & ~63) + ((mg ^ (n & 7)) * 8) + (tl & 7)) = o;
            } else {
                unsigned short* outp = (z == 0) ? Qp : Kp;
                const float sc = (z == 0) ? QSCALE : 1.0f;
                #pragma unroll
                for (int r = 0; r < 4; r++) {
                    const int m = mbase + r;
                    const int pn = (n & ~63) | (((ng ^ (m & 7)) & 7) << 3) | (n & 7);
                    outp[(size_t)m * 1024 + pn] =
                        f32_to_bf16((acc[t][u][r] + bb) * sc);
                }
            }
        }
    }
}

// ---------------------------------------------------------------------------
// Output projection: f32 out, A/W bf16-swizzled. 64x64 tile (1024 blocks,
// 4 blocks/CU — r17 WIN, keep).
// ---------------------------------------------------------------------------
__global__ __launch_bounds__(256)
void gemm_o(const unsigned short* __restrict__ A, const unsigned short* __restrict__ W,
            const float* __restrict__ bias, float* __restrict__ out) {
    constexpr int K = 1024, N = 1024;
    __shared__ unsigned short As[64 * 64];
    __shared__ unsigned short Ws[64 * 64];

    const int tid = threadIdx.x;
    const int w = tid >> 6, lane = tid & 63;
    const int col = lane & 15, quad = lane >> 4;
    const int m0 = blockIdx.x * 64, n0 = blockIdx.y * 64;
    const int wm = (w >> 1) * 32, wn = (w & 1) * 32;

    floatx4 acc[2][2];
    #pragma unroll
    for (int t = 0; t < 2; t++)
        #pragma unroll
        for (int u = 0; u < 2; u++) acc[t][u] = (floatx4){0.f, 0.f, 0.f, 0.f};

    const int lrow = lane >> 3, lcol = (lane & 7) * 8;
    const unsigned short* Ag = A + (size_t)(m0 + w * 16 + lrow) * K + lcol;
    const unsigned short* Wg = W + (size_t)(n0 + w * 16 + lrow) * K + lcol;
    const int po0 = (quad ^ (col & 7)) * 8;
    const int po1 = ((quad + 4) ^ (col & 7)) * 8;

    for (int kb = 0; kb < K; kb += 64) {
        __syncthreads();
        #pragma unroll
        for (int i = 0; i < 2; i++) {
            GL2LDS16(Ag + (size_t)(i * 8) * K + kb, &As[(w * 16 + i * 8) * 64]);
            GL2LDS16(Wg + (size_t)(i * 8) * K + kb, &Ws[(w * 16 + i * 8) * 64]);
        }
        __syncthreads();

        #pragma unroll
        for (int s = 0; s < 2; s++) {
            const int po = s ? po1 : po0;
            short8 af[2], wf[2];
            #pragma unroll
            for (int t = 0; t < 2; t++)
                af[t] = *(const short8*)&As[(wm + t * 16 + col) * 64 + po];
            #pragma unroll
            for (int u = 0; u < 2; u++)
                wf[u] = *(const short8*)&Ws[(wn + u * 16 + col) * 64 + po];
            #pragma unroll
            for (int t = 0; t < 2; t++)
                #pragma unroll
                for (int u = 0; u < 2; u++)
                    acc[t][u] = __builtin_amdgcn_mfma_f32_16x16x32_bf16(af[t], wf[u], acc[t][u], 0, 0, 0);
        }
    }

    #pragma unroll
    for (int u = 0; u < 2; u++) {
        const int n = n0 + wn + u * 16 + col;
        const float bb = bias[n];
        #pragma unroll
        for (int t = 0; t < 2; t++) {
            const int mbase = m0 + wm + t * 16 + quad * 4;
            #pragma unroll
            for (int r = 0; r < 4; r++)
                out[(size_t)(mbase + r) * N + n] = acc[t][u][r] + bb;
        }
    }
}

// ---------------------------------------------------------------------------
// Fused flash attention, 32x32x16 MFMA, S^T formulation, split-K=4 (grid.z).
// r19 = r18 retry MINUS the two r11 risk factors:
//   - __launch_bounds__(256, 4): the r13-proven codegen envelope (VGPR 60
//     natural, no spills). r11's (256,8) forced VGPR<=64 -> heavy spills
//     (690us replay) and post-timing divergence; suspected spill-codegen
//     interaction. At VGPR<=64 the HW allows 8 waves/SIMD anyway, so with
//     LDS 16.4 KB the 2048-block grid still reaches 8 blocks/CU.
//   - Lsum in the Kc region (dead after proj3, no later reader).
// Kept from r18: split-K=4 (8 k-tiles/block), permlane P-redistribution
// (r13-proven, bank-conflict-reduced, LDS 16.4 KB), bf16 Oacch partials
// (numerics verified: r11 first-launch absmax 4.88e-4), XCD swizzle.
// Schedule: r0's proven single-buffer __syncthreads loop.
// ---------------------------------------------------------------------------
__global__ __launch_bounds__(256, 4)
void attn5(const unsigned short* __restrict__ Qp,
           const unsigned short* __restrict__ Kp,
           const unsigned short* __restrict__ Vtp,
           const u64* __restrict__ Mb,
           unsigned short* __restrict__ Oacch, float* __restrict__ Lsum) {
    constexpr int NQ = 2048, NK = 2048;
    __shared__ unsigned short Ks[64 * 64];
    __shared__ unsigned short Vts[64 * 64];

    // XCD swizzle (bijective over the 2048-block grid): flat%8 = XCD under
    // round-robin dispatch; each XCD gets 16 (bh,z) combos x 16 q-blocks.
    const int flat = blockIdx.x + 16 * (blockIdx.y + 32 * blockIdx.z);
    const int xcd = flat & 7, jj = flat >> 3;          // jj in 0..255
    const int combo = xcd + 8 * (jj >> 4);             // 0..127
    const int q0 = (jj & 15) * 128;
    const int bh = combo & 31, z = combo >> 5;         // z in 0..3
    const int b = bh >> 4, h = bh & 15;

    const int tid = threadIdx.x;
    const int wq = tid >> 6, lane = tid & 63;
    const int col = lane & 31, hi = lane >> 5, l7 = lane & 7;
    const int kbeg = z * (NK / 4), kend = kbeg + NK / 4;   // 8 k-tiles

    short8 qf[4];
    {
        const unsigned short* qrow =
            Qp + ((size_t)b * NQ + q0 + wq * 32 + col) * 1024 + h * 64;
        #pragma unroll
        for (int c = 0; c < 4; c++)
            qf[c] = *(const short8*)(qrow + (((c * 2 + hi) ^ l7) * 8));
    }

    floatx16 acc0 = {0,0,0,0,0,0,0,0,0,0,0,0,0,0,0,0};
    floatx16 acc1 = {0,0,0,0,0,0,0,0,0,0,0,0,0,0,0,0};
    float ls0 = 0.f, ls1 = 0.f;

    const int lrow = lane >> 3, lcol = (lane & 7) * 8;
    const unsigned short* Kg =
        Kp + ((size_t)b * NK + wq * 16 + lrow) * 1024 + h * 64 + lcol;
    const unsigned short* Vg =
        Vtp + ((size_t)b * 1024 + h * 64 + wq * 16 + lrow) * NK + lcol;
    const u64* mq = Mb + ((size_t)b * NQ + q0 + wq * 32 + col) * 32;

    for (int k0 = kbeg; k0 < kend; k0 += 64) {
        __syncthreads();
        GL2LDS16(Kg + (size_t)(k0) * 1024,     &Ks[(wq * 16) * 64]);
        GL2LDS16(Kg + (size_t)(k0 + 8) * 1024, &Ks[(wq * 16 + 8) * 64]);
        GL2LDS16(Vg + k0,                      &Vts[(wq * 16) * 64]);
        GL2LDS16(Vg + (size_t)8 * NK + k0,     &Vts[(wq * 16 + 8) * 64]);
        const u64 mw = mq[k0 >> 6];
        __syncthreads();   // compiler-inserted vmcnt(0)+lgkmcnt(0) drain

        #pragma unroll
        for (int g = 0; g < 2; g++) {
            floatx16 s = {0,0,0,0,0,0,0,0,0,0,0,0,0,0,0,0};
            #pragma unroll
            for (int c = 0; c < 4; c++) {
                short8 kf = *(const short8*)&Ks[(g * 32 + col) * 64 + (((c * 2 + hi) ^ l7) * 8)];
                s = __builtin_amdgcn_mfma_f32_32x32x16_bf16(kf, qf[c], s, 0, 0, 0);
            }

            // lane (q=col,hi) holds rows kk = g*32 + rg*8 + 4*hi + r
            const unsigned wbits = (unsigned)(mw >> (g * 32));
            unsigned W0[4], W1[4];
            #pragma unroll
            for (int rg = 0; rg < 4; rg++) {
                const unsigned b4 = (wbits >> (rg * 8 + 4 * hi)) & 0xFu;
                const float p0 = (b4 & 1u) ? __builtin_amdgcn_exp2f(s[rg * 4 + 0]) : 0.f;
                const float p1 = (b4 & 2u) ? __builtin_amdgcn_exp2f(s[rg * 4 + 1]) : 0.f;
                const float p2 = (b4 & 4u) ? __builtin_amdgcn_exp2f(s[rg * 4 + 2]) : 0.f;
                const float p3 = (b4 & 8u) ? __builtin_amdgcn_exp2f(s[rg * 4 + 3]) : 0.f;
                ls0 += p0 + p2;
                ls1 += p1 + p3;
                W0[rg] = pack_bf16x2(p0, p1);   // kk = base+0,+1
                W1[rg] = pack_bf16x2(p2, p3);   // kk = base+2,+3
            }

            // PV A-fragment: one permlane32_swap per word pair
            #pragma unroll
            for (int c2 = 0; c2 < 2; c2++) {
                unsigned a0 = W0[2 * c2], b0 = W0[2 * c2 + 1];
                unsigned a1 = W1[2 * c2], b1 = W1[2 * c2 + 1];
                plswap(a0, b0);   // a0 -> frag word0, b0 -> frag word2
                plswap(a1, b1);   // a1 -> frag word1, b1 -> frag word3
                union { short8 v; unsigned u[4]; } pu;
                pu.u[0] = a0; pu.u[1] = a1; pu.u[2] = b0; pu.u[3] = b1;
                const int kc = g * 2 + c2;
                short8 vf0 = *(const short8*)&Vts[col * 64 + (((kc * 2 + hi) ^ l7) * 8)];
                short8 vf1 = *(const short8*)&Vts[(32 + col) * 64 + (((kc * 2 + hi) ^ l7) * 8)];
                acc0 = __builtin_amdgcn_mfma_f32_32x32x16_bf16(pu.v, vf0, acc0, 0, 0, 0);
                acc1 = __builtin_amdgcn_mfma_f32_32x32x16_bf16(pu.v, vf1, acc1, 0, 0, 0);
            }
        }
    }

    float lsum = ls0 + ls1;
    lsum += __shfl_xor(lsum, 32);

    // Partial O in bf16 (numerics verified in r11's passing first launch)
    const size_t base = ((size_t)(z * 32 + bh) * NQ + q0 + wq * 32) * 64;
    #pragma unroll
    for (int rg = 0; rg < 4; rg++)
        #pragma unroll
        for (int r = 0; r < 4; r++) {
            const int qrow = rg * 8 + 4 * hi + r;
            Oacch[base + (size_t)qrow * 64 + col]      = f32_to_bf16(acc0[rg * 4 + r]);
            Oacch[base + (size_t)qrow * 64 + 32 + col] = f32_to_bf16(acc1[rg * 4 + r]);
        }
    if (hi == 0)
        Lsum[(size_t)(z * 32 + bh) * NQ + q0 + wq * 32 + col] = lsum;
}

// ---------------------------------------------------------------------------
// Combine split-K=4 quarters: Ohp = (sum_z Oacc_z) / (sum_z l_z + eps),
// bf16 partials in, bf16 swizzled out.
// ---------------------------------------------------------------------------
__global__ __launch_bounds__(256)
void combine4(const unsigned short* __restrict__ Oacch,
              const float* __restrict__ Lsum,
              unsigned short* __restrict__ Ohp) {
    const int T = blockIdx.x * 256 + threadIdx.x;
    const int d0 = (T & 15) * 4;
    const int q = (T >> 4) & 2047;
    const int bh = T >> 15;                     // 0..31
    const int b = bh >> 4, h = bh & 15;

    float acc[4] = {0.f, 0.f, 0.f, 0.f};
    float l = 1e-8f;
    #pragma unroll
    for (int zz = 0; zz < 4; zz++) {
        const size_t o = ((size_t)(zz * 32 + bh) * 2048 + q) * 64 + d0;
        ushort4v a = *(const ushort4v*)(Oacch + o);
        #pragma unroll
        for (int j = 0; j < 4; j++) acc[j] += bf16_to_f32(a[j]);
        l += Lsum[(size_t)(zz * 32 + bh) * 2048 + q];
    }
    const float inv = 1.0f / l;
    ushort4v o;
    #pragma unroll
    for (int j = 0; j < 4; j++) o[j] = f32_to_bf16(acc[j] * inv);
    const int g = d0 >> 3, qg = q & 7;
    *(ushort4v*)(Ohp + ((size_t)b * 2048 + q) * 1024 + h * 64 +
                 ((g ^ qg) * 8) + (d0 & 7)) = o;
}

extern "C" void kernel_launch(void* const* d_in, const int* in_sizes, int n_in,
                              void* d_out, int out_size, void* d_ws, size_t ws_size,
                              hipStream_t stream) {
    const float* Q    = (const float*)d_in[0];
    const float* K    = (const float*)d_in[1];
    const int*   mask = (const int*)d_in[2];
    const float* Wq   = (const float*)d_in[3];
    const float* bq   = (const float*)d_in[4];
    const float* Wk   = (const float*)d_in[5];
    const float* bk   = (const float*)d_in[6];
    const float* Wv   = (const float*)d_in[7];
    const float* bv   = (const float*)d_in[8];
    const float* Wo   = (const float*)d_in[9];
    const float* bo   = (const float*)d_in[10];
    float* out = (float*)d_out;

    constexpr int M = 2 * 2048;
    constexpr size_t MB8 = (size_t)M * 1024 * sizeof(unsigned short);      // 8 MB
    constexpr size_t MB2 = (size_t)1024 * 1024 * sizeof(unsigned short);   // 2 MB
    constexpr size_t MBMASK = (size_t)2 * 2048 * 2048 / 64 * 8;            // 1 MB
    constexpr size_t BASE = 5 * MB8 + 4 * MB2 + MBMASK;
    constexpr size_t OACC_SZ = (size_t)4 * 32 * 2048 * 64 * 2;             // 33.5 MB bf16

    char* ws = (char*)d_ws;
    unsigned short* Qc  = (unsigned short*)(ws);              // dead after proj3; reused as Ohp
    unsigned short* Ohp = (unsigned short*)(ws);
    unsigned short* Kc  = (unsigned short*)(ws + MB8);        // dead after proj3; reused as Lsum
    unsigned short* Wqc = (unsigned short*)(ws + 2 * MB8);
    unsigned short* Wkc = (unsigned short*)(ws + 2 * MB8 + MB2);
    unsigned short* Wvc = (unsigned short*)(ws + 2 * MB8 + 2 * MB2);
    unsigned short* Woc = (unsigned short*)(ws + 2 * MB8 + 3 * MB2);
    unsigned short* Qp  = (unsigned short*)(ws + 2 * MB8 + 4 * MB2);
    unsigned short* Kp  = (unsigned short*)(ws + 3 * MB8 + 4 * MB2);
    unsigned short* Vtp = (unsigned short*)(ws + 4 * MB8 + 4 * MB2);
    u64*            Mb  = (u64*)(ws + 5 * MB8 + 4 * MB2);
    unsigned short* Oacch = (unsigned short*)(ws + BASE);
    // Lsum (128 x 2048 f32 = 1 MB) lives in the Kc region — dead after
    // proj3, no later reader — keeps peak workspace within the proven
    // BASE + 33.5 MB budget.
    float*          Lsum  = (float*)(ws + MB8);

    dim3 blk(256);

    prep<<<dim3(12288 + 32768), blk, 0, stream>>>(
        Q, K, Wq, Wk, Wv, Wo, mask, Qc, Kc, Wqc, Wkc, Wvc, Woc, Mb);

    proj3<<<dim3(M / 128, 1024 / 128, 3), blk, 0, stream>>>(
        Qc, Kc, Wqc, Wkc, Wvc, bq, bk, bv, Qp, Kp, Vtp);

    attn5<<<dim3(2048 / 128, 32, 4), blk, 0, stream>>>(
        Qp, Kp, Vtp, Mb, Oacch, Lsum);
    combine4<<<dim3(4096), blk, 0, stream>>>(Oacch, Lsum, Ohp);

    gemm_o<<<dim3(M / 64, 1024 / 64), blk, 0, stream>>>(Ohp, Woc, bo, out);
}